// Round 1
// 11612.518 us; speedup vs baseline: 1.6152x; 1.6152x over previous
//
#include <hip/hip_runtime.h>
#include <hip/hip_bf16.h>
#include <stdint.h>

// Problem constants
#define T_STEPS 256
#define BATCH   32
#define HID     1024
#define KDIM    2048   // input width of every layer (D_IN = 2H = 2048)
#define NDIM    6144   // 2 dirs * 3H
#define MDIM    8192   // T*B

typedef __attribute__((ext_vector_type(8))) short bfrag;   // 8 bf16 = 4 VGPRs
typedef __attribute__((ext_vector_type(4))) float ffrag;   // 4 f32 accum

__device__ inline unsigned short f2bf(float f) {
  __hip_bfloat16 h = __float2bfloat16(f);
  unsigned short u;
  __builtin_memcpy(&u, &h, 2);
  return u;
}

__device__ inline void gld_lds16(const void* g, void* l) {
  __builtin_amdgcn_global_load_lds(
      (const __attribute__((address_space(1))) void*)g,
      (__attribute__((address_space(3))) void*)l,
      16, 0, 0);
}

// ---------------------------------------------------------------- converts
__global__ __launch_bounds__(256) void f32_to_bf16_k(
    const float* __restrict__ src, unsigned short* __restrict__ dst, int n4) {
  int i = blockIdx.x * 256 + threadIdx.x;
  if (i >= n4) return;
  float4 v = ((const float4*)src)[i];
  ushort4 o;
  o.x = f2bf(v.x); o.y = f2bf(v.y); o.z = f2bf(v.z); o.w = f2bf(v.w);
  ((ushort4*)dst)[i] = o;
}

// ---------------------------------------------------------------- GEMM (xp)
// C[m][n] = sum_k A[m][k] * Bw[n][k] + bias[n]
// A: (8192,2048) bf16 rm; Bw: (6144,2048) bf16 rm; C f32.
__global__ __launch_bounds__(256) void gemm_xp(
    const unsigned short* __restrict__ A,
    const unsigned short* __restrict__ Bw,
    const float* __restrict__ bias,
    float* __restrict__ C) {
  __shared__ __align__(16) unsigned short Asl[128 * 32];
  __shared__ __align__(16) unsigned short Bsl[128 * 32];
  const int tid  = threadIdx.x;
  const int wave = tid >> 6;
  const int lane = tid & 63;
  const int quad = lane >> 4;
  const int lm   = lane & 15;
  const int m0 = blockIdx.x * 128;
  const int n0 = blockIdx.y * 128;
  const int wm = (wave & 1) * 64;
  const int wn = (wave >> 1) * 64;

  ffrag acc[4][4];
#pragma unroll
  for (int a = 0; a < 4; a++)
#pragma unroll
    for (int b = 0; b < 4; b++) {
      ffrag z = {0.0f, 0.0f, 0.0f, 0.0f};
      acc[a][b] = z;
    }

  const int r = tid >> 2;
  const int c = tid & 3;
  const unsigned short* Ag0 = A  + (size_t)(m0 + r) * KDIM + c * 8;
  const unsigned short* Ag1 = Ag0 + (size_t)64 * KDIM;
  const unsigned short* Bg0 = Bw + (size_t)(n0 + r) * KDIM + c * 8;
  const unsigned short* Bg1 = Bg0 + (size_t)64 * KDIM;
  char* Al = (char*)Asl + wave * 1024;
  char* Bl = (char*)Bsl + wave * 1024;

  for (int kk = 0; kk < KDIM; kk += 32) {
    __syncthreads();
    gld_lds16(Ag0 + kk, Al);
    gld_lds16(Ag1 + kk, Al + 4096);
    gld_lds16(Bg0 + kk, Bl);
    gld_lds16(Bg1 + kk, Bl + 4096);
    __syncthreads();

    bfrag af[4], bf[4];
#pragma unroll
    for (int mt = 0; mt < 4; mt++)
      af[mt] = *(const bfrag*)((const char*)Asl + (wm + mt * 16 + lm) * 64 + quad * 16);
#pragma unroll
    for (int nt = 0; nt < 4; nt++)
      bf[nt] = *(const bfrag*)((const char*)Bsl + (wn + nt * 16 + lm) * 64 + quad * 16);
#pragma unroll
    for (int mt = 0; mt < 4; mt++)
#pragma unroll
      for (int nt = 0; nt < 4; nt++)
        acc[mt][nt] = __builtin_amdgcn_mfma_f32_16x16x32_bf16(
            af[mt], bf[nt], acc[mt][nt], 0, 0, 0);
  }

#pragma unroll
  for (int mt = 0; mt < 4; mt++) {
#pragma unroll
    for (int nt = 0; nt < 4; nt++) {
      int mrow = m0 + wm + mt * 16 + quad * 4;
      int ncol = n0 + wn + nt * 16 + lm;
      float bi = bias[ncol];
#pragma unroll
      for (int i = 0; i < 4; i++)
        C[(size_t)(mrow + i) * NDIM + ncol] = acc[mt][nt][i] + bi;
    }
  }
}

// ---------------------------------------------------------------- custom grid barrier
// Monotonic counter: each block arrives once (release), spins on a relaxed
// agent-scope load until count reaches target, then acquires. Same fence
// semantics as cg::grid_group::sync (which the previous, passing version used),
// but without the long s_sleep backoff quantization in the ROCm cg spin loop.
__device__ inline void gbar(unsigned* cnt, unsigned target) {
  __syncthreads();   // all block stores drained (vmcnt) before arrive
  if (threadIdx.x == 0) {
    __hip_atomic_fetch_add(cnt, 1u, __ATOMIC_RELEASE, __HIP_MEMORY_SCOPE_AGENT);
    while (__hip_atomic_load(cnt, __ATOMIC_RELAXED, __HIP_MEMORY_SCOPE_AGENT) < target)
      __builtin_amdgcn_s_sleep(1);
    (void)__hip_atomic_load(cnt, __ATOMIC_ACQUIRE, __HIP_MEMORY_SCOPE_AGENT);
  }
  __syncthreads();
}

// ---------------------------------------------------------------- persistent scan
// One cooperative launch per layer; 256 steps inside, one custom barrier/step.
// grid 128: blk>>6 = dir, (blk&63)*16 = owned h-output base j0.
// 384 threads = 6 waves: wave = g*2+mt (g=gate 0..2, mt=b-half).
// W_hh fragments live in VGPRs for the whole scan (32 bfrags = 128 VGPR/lane).
// fp32 h carry lives in LDS (block-local); only the bf16 shadow goes to global
// for the all-to-all MFMA A-operand reads.
__global__ __launch_bounds__(384, 1) void gru_scan(
    const float* __restrict__ xp,          // (T*B, 6144), bias_ih included
    const unsigned short* __restrict__ Wbf,// (2,3072,1024) bf16, this layer
    const float* __restrict__ bhh,         // (2,3072) this layer
    const float* __restrict__ h0,          // (2,32,1024) this layer
    unsigned short* __restrict__ hbA, unsigned short* __restrict__ hbB,
    unsigned* __restrict__ bar,            // per-layer barrier counter (zeroed)
    unsigned short* __restrict__ out_bf,   // (T,B,2048) bf16 or null
    float* __restrict__ out_f32) {         // (T,B,2048) f32 (final layer)
  __shared__ float gbuf[3][32][17];        // [gate][b][j], +1 pad
  __shared__ float hloc[32][16];           // fp32 h carry, block-local slice

  const int blk  = blockIdx.x;
  const int d    = blk >> 6;
  const int j0   = (blk & 63) * 16;
  const int tid  = threadIdx.x;
  const int wave = tid / 64;
  const int lane = tid & 63;
  const int quad = lane >> 4;
  const int lm   = lane & 15;
  const int g    = wave >> 1;              // gate
  const int mt   = wave & 1;               // b-half

  // ---- preload this wave's W_hh tile into registers (persists all 256 steps)
  const unsigned short* wrow =
      Wbf + ((size_t)(d * 3072 + g * 1024 + j0 + lm)) * HID + quad * 8;
  bfrag wreg[32];
#pragma unroll
  for (int kk = 0; kk < 32; kk++)
    wreg[kk] = *(const bfrag*)(wrow + kk * 32);

  const int arow_off = (d * 32 + mt * 16 + lm) * HID + quad * 8;

  // ---- init h: fp32 into LDS, bf16 shadow into global
  for (int o = tid; o < 512; o += 384) {
    int b = o >> 4, j = o & 15;
    float v = h0[(d * 32 + b) * HID + j0 + j];
    hloc[b][j] = v;
    hbA[(d * 32 + b) * HID + j0 + j] = f2bf(v);
  }

  // ---- hoist per-output b_hh (constant across steps)
  float bh_r[2], bh_z[2], bh_n[2];
#pragma unroll
  for (int u = 0; u < 2; u++) {
    int o = tid + u * 384;
    if (o < 512) {
      int jg = j0 + (o & 15);
      bh_r[u] = bhh[d * 3072 + jg];
      bh_z[u] = bhh[d * 3072 + 1024 + jg];
      bh_n[u] = bhh[d * 3072 + 2048 + jg];
    }
  }

  unsigned bt = 128;
  gbar(bar, bt);                            // h0 shadow visible device-wide

  const unsigned short* hb_prev = hbA;
  unsigned short* hb_next = hbB;

  for (int s = 0; s < T_STEPS; s++) {
    const int t = d ? (T_STEPS - 1 - s) : s;

    // ---- prefetch xp[t] (independent of h): latency hides under MFMA phase
    float pxr[2], pxz[2], pxn[2];
#pragma unroll
    for (int u = 0; u < 2; u++) {
      int o = tid + u * 384;
      if (o < 512) {
        int b = o >> 4, jg = j0 + (o & 15);
        const float* xrow = xp + ((size_t)t * BATCH + b) * NDIM + d * 3072;
        pxr[u] = __builtin_nontemporal_load(xrow + jg);
        pxz[u] = __builtin_nontemporal_load(xrow + 1024 + jg);
        pxn[u] = __builtin_nontemporal_load(xrow + 2048 + jg);
      }
    }

    // ---- MFMA phase: acc = h_prev x W_g^T, W from registers, dual chains
    ffrag acc0 = {0.0f, 0.0f, 0.0f, 0.0f};
    ffrag acc1 = {0.0f, 0.0f, 0.0f, 0.0f};
    const unsigned short* ap = hb_prev + arow_off;
#pragma unroll
    for (int kk = 0; kk < 32; kk += 2) {
      bfrag a0 = *(const bfrag*)(ap + kk * 32);
      bfrag a1 = *(const bfrag*)(ap + kk * 32 + 32);
      acc0 = __builtin_amdgcn_mfma_f32_16x16x32_bf16(a0, wreg[kk],     acc0, 0, 0, 0);
      acc1 = __builtin_amdgcn_mfma_f32_16x16x32_bf16(a1, wreg[kk + 1], acc1, 0, 0, 0);
    }

    __syncthreads();   // previous epilogue's gbuf reads complete
    // C/D layout: col(n)=lm -> j, row(m)=quad*4+i -> b (within half mt)
#pragma unroll
    for (int i = 0; i < 4; i++)
      gbuf[g][mt * 16 + quad * 4 + i][lm] = acc0[i] + acc1[i];
    __syncthreads();

    // ---- gate math + stores (512 outputs over 384 threads)
#pragma unroll
    for (int u = 0; u < 2; u++) {
      int o = tid + u * 384;
      if (o < 512) {
        int b = o >> 4, j = o & 15;
        int jg = j0 + j;
        float hr = gbuf[0][b][j] + bh_r[u];
        float hz = gbuf[1][b][j] + bh_z[u];
        float hn = gbuf[2][b][j] + bh_n[u];
        float rr = 1.0f / (1.0f + __expf(-(pxr[u] + hr)));
        float zz = 1.0f / (1.0f + __expf(-(pxz[u] + hz)));
        float nn = tanhf(pxn[u] + rr * hn);
        float hp = hloc[b][j];
        float hv = (1.0f - zz) * nn + zz * hp;
        hloc[b][j] = hv;
        unsigned short hvb = f2bf(hv);
        hb_next[(d * 32 + b) * HID + jg] = hvb;
        size_t oi = ((size_t)t * BATCH + b) * 2048 + d * HID + jg;
        if (out_bf) __builtin_nontemporal_store(hvb, &out_bf[oi]);
        else        __builtin_nontemporal_store(hv, &out_f32[oi]);
      }
    }

    bt += 128;
    gbar(bar, bt);     // h_next visible device-wide before next step reads it

    const unsigned short* tb = hb_prev;
    hb_prev = hb_next;
    hb_next = (unsigned short*)tb;
  }
}

// ---------------------------------------------------------------- launch
extern "C" void kernel_launch(void* const* d_in, const int* in_sizes, int n_in,
                              void* d_out, int out_size, void* d_ws, size_t ws_size,
                              hipStream_t stream) {
  const float* x    = (const float*)d_in[0];  // (256,32,2048)
  const float* h0   = (const float*)d_in[1];  // (6,32,1024)
  const float* W_ih = (const float*)d_in[2];  // (3,2,3072,2048)
  const float* W_hh = (const float*)d_in[3];  // (3,2,3072,1024)
  const float* b_ih = (const float*)d_in[4];  // (3,2,3072)
  const float* b_hh = (const float*)d_in[5];  // (3,2,3072)
  float* out = (float*)d_out;                 // (256,32,2048) f32

  // workspace carve
  char* w = (char*)d_ws;
  float* xp = (float*)w;                    w += (size_t)MDIM * NDIM * 4;     // 201.3 MB
  unsigned short* act = (unsigned short*)w; w += (size_t)MDIM * KDIM * 2;     // 33.6 MB
  unsigned short* Wub = (unsigned short*)w; w += (size_t)2 * 3072 * KDIM * 2; // 25.2 MB (union: W_ih-bf16 then W_hh-bf16)
  unsigned short* hbA = (unsigned short*)w; w += (size_t)2 * BATCH * HID * 2;
  unsigned short* hbB = (unsigned short*)w; w += (size_t)2 * BATCH * HID * 2;
  unsigned* bar = (unsigned*)w;             w += 256;                          // 3 barrier counters

  // zero the per-layer barrier counters (stream-ordered; graph-capture safe)
  hipMemsetAsync(bar, 0, 3 * sizeof(unsigned), stream);

  // x -> bf16 (layer-0 GEMM A operand)
  f32_to_bf16_k<<<16384, 256, 0, stream>>>(x, act, MDIM * KDIM / 4);

  for (int l = 0; l < 3; l++) {
    // W_ih[l] -> bf16 into union buffer
    f32_to_bf16_k<<<12288, 256, 0, stream>>>(
        W_ih + (size_t)l * 2 * 3072 * KDIM, Wub, 2 * 3072 * KDIM / 4);
    // xp = act * W_ih^T + b_ih
    dim3 gg(MDIM / 128, NDIM / 128);
    gemm_xp<<<gg, 256, 0, stream>>>(act, Wub, b_ih + l * NDIM, xp);
    // W_hh[l] -> bf16 into the same union buffer
    f32_to_bf16_k<<<6144, 256, 0, stream>>>(
        W_hh + (size_t)l * 2 * 3072 * HID, Wub, 2 * 3072 * HID / 4);

    // persistent cooperative scan over all 256 steps
    const float* xp_c = xp;
    const unsigned short* Wbf_c = Wub;
    const float* bhl = b_hh + l * NDIM;
    const float* h0l = h0 + (size_t)l * 2 * BATCH * HID;
    unsigned short* hbA_ = hbA; unsigned short* hbB_ = hbB;
    unsigned* bar_ = bar + l;
    unsigned short* dst_bf = (l == 2) ? nullptr : act;
    float* dst_f32 = (l == 2) ? out : nullptr;
    void* args[] = {
        (void*)&xp_c, (void*)&Wbf_c, (void*)&bhl, (void*)&h0l,
        (void*)&hbA_, (void*)&hbB_, (void*)&bar_,
        (void*)&dst_bf, (void*)&dst_f32,
    };
    hipLaunchCooperativeKernel((void*)gru_scan, dim3(128), dim3(384),
                               args, 0, stream);
  }
}

// Round 2
// 10699.344 us; speedup vs baseline: 1.7531x; 1.0853x over previous
//
#include <hip/hip_runtime.h>
#include <hip/hip_bf16.h>
#include <stdint.h>

// Problem constants
#define T_STEPS 256
#define BATCH   32
#define HID     1024
#define KDIM    2048   // input width of every layer (D_IN = 2H = 2048)
#define NDIM    6144   // 2 dirs * 3H
#define MDIM    8192   // T*B

typedef __attribute__((ext_vector_type(8))) short bfrag;   // 8 bf16 = 4 VGPRs
typedef __attribute__((ext_vector_type(4))) float ffrag;   // 4 f32 accum

typedef union {
  bfrag f;
  unsigned long long q[2];
} abuf;

__device__ inline unsigned short f2bf(float f) {
  __hip_bfloat16 h = __float2bfloat16(f);
  unsigned short u;
  __builtin_memcpy(&u, &h, 2);
  return u;
}

__device__ inline void gld_lds16(const void* g, void* l) {
  __builtin_amdgcn_global_load_lds(
      (const __attribute__((address_space(1))) void*)g,
      (__attribute__((address_space(3))) void*)l,
      16, 0, 0);
}

// ---------------------------------------------------------------- converts
__global__ __launch_bounds__(256) void f32_to_bf16_k(
    const float* __restrict__ src, unsigned short* __restrict__ dst, int n4) {
  int i = blockIdx.x * 256 + threadIdx.x;
  if (i >= n4) return;
  float4 v = ((const float4*)src)[i];
  ushort4 o;
  o.x = f2bf(v.x); o.y = f2bf(v.y); o.z = f2bf(v.z); o.w = f2bf(v.w);
  ((ushort4*)dst)[i] = o;
}

// ---------------------------------------------------------------- GEMM (xp)
// C[m][n] = sum_k A[m][k] * Bw[n][k] + bias[n]
// A: (8192,2048) bf16 rm; Bw: (6144,2048) bf16 rm; C f32.
__global__ __launch_bounds__(256) void gemm_xp(
    const unsigned short* __restrict__ A,
    const unsigned short* __restrict__ Bw,
    const float* __restrict__ bias,
    float* __restrict__ C) {
  __shared__ __align__(16) unsigned short Asl[128 * 32];
  __shared__ __align__(16) unsigned short Bsl[128 * 32];
  const int tid  = threadIdx.x;
  const int wave = tid >> 6;
  const int lane = tid & 63;
  const int quad = lane >> 4;
  const int lm   = lane & 15;
  const int m0 = blockIdx.x * 128;
  const int n0 = blockIdx.y * 128;
  const int wm = (wave & 1) * 64;
  const int wn = (wave >> 1) * 64;

  ffrag acc[4][4];
#pragma unroll
  for (int a = 0; a < 4; a++)
#pragma unroll
    for (int b = 0; b < 4; b++) {
      ffrag z = {0.0f, 0.0f, 0.0f, 0.0f};
      acc[a][b] = z;
    }

  const int r = tid >> 2;
  const int c = tid & 3;
  const unsigned short* Ag0 = A  + (size_t)(m0 + r) * KDIM + c * 8;
  const unsigned short* Ag1 = Ag0 + (size_t)64 * KDIM;
  const unsigned short* Bg0 = Bw + (size_t)(n0 + r) * KDIM + c * 8;
  const unsigned short* Bg1 = Bg0 + (size_t)64 * KDIM;
  char* Al = (char*)Asl + wave * 1024;
  char* Bl = (char*)Bsl + wave * 1024;

  for (int kk = 0; kk < KDIM; kk += 32) {
    __syncthreads();
    gld_lds16(Ag0 + kk, Al);
    gld_lds16(Ag1 + kk, Al + 4096);
    gld_lds16(Bg0 + kk, Bl);
    gld_lds16(Bg1 + kk, Bl + 4096);
    __syncthreads();

    bfrag af[4], bf[4];
#pragma unroll
    for (int mt = 0; mt < 4; mt++)
      af[mt] = *(const bfrag*)((const char*)Asl + (wm + mt * 16 + lm) * 64 + quad * 16);
#pragma unroll
    for (int nt = 0; nt < 4; nt++)
      bf[nt] = *(const bfrag*)((const char*)Bsl + (wn + nt * 16 + lm) * 64 + quad * 16);
#pragma unroll
    for (int mt = 0; mt < 4; mt++)
#pragma unroll
      for (int nt = 0; nt < 4; nt++)
        acc[mt][nt] = __builtin_amdgcn_mfma_f32_16x16x32_bf16(
            af[mt], bf[nt], acc[mt][nt], 0, 0, 0);
  }

#pragma unroll
  for (int mt = 0; mt < 4; mt++) {
#pragma unroll
    for (int nt = 0; nt < 4; nt++) {
      int mrow = m0 + wm + mt * 16 + quad * 4;
      int ncol = n0 + wn + nt * 16 + lm;
      float bi = bias[ncol];
#pragma unroll
      for (int i = 0; i < 4; i++)
        C[(size_t)(mrow + i) * NDIM + ncol] = acc[mt][nt][i] + bi;
    }
  }
}

// ---------------------------------------------------------------- persistent scan
// One cooperative launch per layer; 256 steps inside.
// grid 128: blk>>6 = dir, (blk&63)*16 = owned h-output base j0.
// 384 threads = 6 waves: wave = g*2+mt (g=gate 0..2, mt=b-half).
//
// Coherence design (no buffer_wbl2/buffer_inv anywhere in the step loop):
//  - h bf16 shadow is written with RELAXED agent-scope atomic stores (write-
//    through sc1 -> lands at the Infinity-Cache coherence point, bypasses L2)
//  - h is read with RELAXED agent-scope atomic loads (sc1 -> served by L3,
//    immune to stale per-XCD L1/L2 copies)
//  - the per-step barrier is therefore a purely RELAXED monotonic counter:
//    __syncthreads() drains each wave's vmcnt (stores are at L3 once retired),
//    then one fetch_add per block, relaxed spin, __syncthreads().
//  - directions never exchange data during the scan -> one counter per
//    direction (64 blocks each, 256B apart).
__global__ __launch_bounds__(384, 1) void gru_scan(
    const float* __restrict__ xp,          // (T*B, 6144), bias_ih included
    const unsigned short* __restrict__ Wbf,// (2,3072,1024) bf16, this layer
    const float* __restrict__ bhh,         // (2,3072) this layer
    const float* __restrict__ h0,          // (2,32,1024) this layer
    unsigned short* __restrict__ hbA, unsigned short* __restrict__ hbB,
    unsigned* __restrict__ bar,            // per-(layer,dir) counters
    unsigned short* __restrict__ out_bf,   // (T,B,2048) bf16 or null
    float* __restrict__ out_f32) {         // (T,B,2048) f32 (final layer)
  __shared__ float gbuf[3][32][17];        // [gate][b][j], +1 pad
  __shared__ float hloc[32][16];           // fp32 h carry, block-local slice

  const int blk  = blockIdx.x;
  const int d    = blk >> 6;
  const int j0   = (blk & 63) * 16;
  const int tid  = threadIdx.x;
  const int lane = tid & 63;
  const int quad = lane >> 4;
  const int lm   = lane & 15;
  const int g    = (tid / 64) >> 1;        // gate
  const int mt   = (tid / 64) & 1;         // b-half

  unsigned* mybar = bar + d * 64;          // 256B apart per direction

  // gate-phase mapping: tid<256 handle b=tid>>3, j = (tid&7)*2 + {0,1}
  const int gb  = tid >> 3;
  const int gj  = (tid & 7) * 2;
  const bool gact = (tid < 256);

  // ---- init h: fp32 into LDS, bf16 shadow to L3 (agent-scope stores)
  if (gact) {
    float v0 = h0[(d * 32 + gb) * HID + j0 + gj];
    float v1 = h0[(d * 32 + gb) * HID + j0 + gj + 1];
    hloc[gb][gj]     = v0;
    hloc[gb][gj + 1] = v1;
    unsigned pk = (unsigned)f2bf(v0) | ((unsigned)f2bf(v1) << 16);
    __hip_atomic_store((unsigned*)&hbA[(d * 32 + gb) * HID + j0 + gj], pk,
                       __ATOMIC_RELAXED, __HIP_MEMORY_SCOPE_AGENT);
  }

  // ---- hoist b_hh (constant across steps)
  float bh_r0 = 0, bh_r1 = 0, bh_z0 = 0, bh_z1 = 0, bh_n0 = 0, bh_n1 = 0;
  if (gact) {
    int jg = j0 + gj;
    bh_r0 = bhh[d * 3072 + jg];        bh_r1 = bhh[d * 3072 + jg + 1];
    bh_z0 = bhh[d * 3072 + 1024 + jg]; bh_z1 = bhh[d * 3072 + 1024 + jg + 1];
    bh_n0 = bhh[d * 3072 + 2048 + jg]; bh_n1 = bhh[d * 3072 + 2048 + jg + 1];
  }

  // fragment base offsets
  const unsigned short* wrow =
      Wbf + ((size_t)(d * 3072 + g * 1024 + j0 + lm)) * HID + quad * 8;
  const int arow_off = (d * 32 + mt * 16 + lm) * HID + quad * 8;

  // ---- initial barrier: h0 shadow visible device-wide
  unsigned bt = 64;
  __syncthreads();
  if (tid == 0)
    __hip_atomic_fetch_add(mybar, 1u, __ATOMIC_RELAXED, __HIP_MEMORY_SCOPE_AGENT);

  // prologue xp prefetch for s=0 (overlaps the spin)
  float2 pxr, pxz, pxn;
  {
    const int t0 = d ? (T_STEPS - 1) : 0;
    const float* xrow = xp + ((size_t)t0 * BATCH + gb) * NDIM + d * 3072 + j0 + gj;
    if (gact) {
      pxr = *(const float2*)(xrow);
      pxz = *(const float2*)(xrow + 1024);
      pxn = *(const float2*)(xrow + 2048);
    }
  }
  if (tid == 0) {
    while (__hip_atomic_load(mybar, __ATOMIC_RELAXED, __HIP_MEMORY_SCOPE_AGENT) < bt)
      __builtin_amdgcn_s_sleep(1);
  }
  __syncthreads();

  const unsigned short* hb_prev = hbA;
  unsigned short* hb_next = hbB;

  for (int s = 0; s < T_STEPS; s++) {
    const int t = d ? (T_STEPS - 1 - s) : s;

    // ---- A preload: 32 fragments of h_prev via agent-scope (L3) loads
    abuf a[32];
    const unsigned short* ap = hb_prev + arow_off;
#pragma unroll
    for (int kk = 0; kk < 32; kk++) {
      a[kk].q[0] = __hip_atomic_load((const unsigned long long*)(ap + kk * 32),
                                     __ATOMIC_RELAXED, __HIP_MEMORY_SCOPE_AGENT);
      a[kk].q[1] = __hip_atomic_load((const unsigned long long*)(ap + kk * 32 + 4),
                                     __ATOMIC_RELAXED, __HIP_MEMORY_SCOPE_AGENT);
    }

    // ---- MFMA: acc = h_prev x W_g^T (W from L2, dual chains)
    ffrag acc0 = {0.0f, 0.0f, 0.0f, 0.0f};
    ffrag acc1 = {0.0f, 0.0f, 0.0f, 0.0f};
#pragma unroll
    for (int kk = 0; kk < 32; kk += 2) {
      bfrag w0 = *(const bfrag*)(wrow + kk * 32);
      bfrag w1 = *(const bfrag*)(wrow + (kk + 1) * 32);
      acc0 = __builtin_amdgcn_mfma_f32_16x16x32_bf16(a[kk].f,     w0, acc0, 0, 0, 0);
      acc1 = __builtin_amdgcn_mfma_f32_16x16x32_bf16(a[kk + 1].f, w1, acc1, 0, 0, 0);
    }

    __syncthreads();   // previous gate phase's gbuf reads complete
    // C/D layout: col(n)=lm -> j, row(m)=quad*4+i -> b (within half mt)
#pragma unroll
    for (int i = 0; i < 4; i++)
      gbuf[g][mt * 16 + quad * 4 + i][lm] = acc0[i] + acc1[i];
    __syncthreads();

    // ---- gate math + stores (tid<256: 2 adjacent j each)
    if (gact) {
      int jg = j0 + gj;
      float hr0 = gbuf[0][gb][gj]     + bh_r0;
      float hr1 = gbuf[0][gb][gj + 1] + bh_r1;
      float hz0 = gbuf[1][gb][gj]     + bh_z0;
      float hz1 = gbuf[1][gb][gj + 1] + bh_z1;
      float hn0 = gbuf[2][gb][gj]     + bh_n0;
      float hn1 = gbuf[2][gb][gj + 1] + bh_n1;
      float rr0 = 1.0f / (1.0f + __expf(-(pxr.x + hr0)));
      float rr1 = 1.0f / (1.0f + __expf(-(pxr.y + hr1)));
      float zz0 = 1.0f / (1.0f + __expf(-(pxz.x + hz0)));
      float zz1 = 1.0f / (1.0f + __expf(-(pxz.y + hz1)));
      float nn0 = tanhf(pxn.x + rr0 * hn0);
      float nn1 = tanhf(pxn.y + rr1 * hn1);
      float hv0 = (1.0f - zz0) * nn0 + zz0 * hloc[gb][gj];
      float hv1 = (1.0f - zz1) * nn1 + zz1 * hloc[gb][gj + 1];
      hloc[gb][gj]     = hv0;
      hloc[gb][gj + 1] = hv1;
      unsigned pk = (unsigned)f2bf(hv0) | ((unsigned)f2bf(hv1) << 16);
      __hip_atomic_store((unsigned*)&hb_next[(d * 32 + gb) * HID + jg], pk,
                         __ATOMIC_RELAXED, __HIP_MEMORY_SCOPE_AGENT);
      size_t oi = ((size_t)t * BATCH + gb) * 2048 + d * HID + jg;
      if (out_bf) {
        *(unsigned*)&out_bf[oi] = pk;
      } else {
        float2 ov; ov.x = hv0; ov.y = hv1;
        *(float2*)&out_f32[oi] = ov;
      }
    }

    // ---- barrier: arrive, prefetch xp[t+1] under the spin, wait
    bt += 64;
    __syncthreads();   // drains every wave's stores (write-through -> at L3)
    if (tid == 0)
      __hip_atomic_fetch_add(mybar, 1u, __ATOMIC_RELAXED, __HIP_MEMORY_SCOPE_AGENT);
    if (gact) {
      int s2 = (s + 1 < T_STEPS) ? s + 1 : s;
      int t2 = d ? (T_STEPS - 1 - s2) : s2;
      const float* xrow = xp + ((size_t)t2 * BATCH + gb) * NDIM + d * 3072 + j0 + gj;
      pxr = *(const float2*)(xrow);
      pxz = *(const float2*)(xrow + 1024);
      pxn = *(const float2*)(xrow + 2048);
    }
    if (tid == 0) {
      while (__hip_atomic_load(mybar, __ATOMIC_RELAXED, __HIP_MEMORY_SCOPE_AGENT) < bt)
        __builtin_amdgcn_s_sleep(1);
    }
    __syncthreads();

    const unsigned short* tb = hb_prev;
    hb_prev = hb_next;
    hb_next = (unsigned short*)tb;
  }
}

// ---------------------------------------------------------------- launch
extern "C" void kernel_launch(void* const* d_in, const int* in_sizes, int n_in,
                              void* d_out, int out_size, void* d_ws, size_t ws_size,
                              hipStream_t stream) {
  const float* x    = (const float*)d_in[0];  // (256,32,2048)
  const float* h0   = (const float*)d_in[1];  // (6,32,1024)
  const float* W_ih = (const float*)d_in[2];  // (3,2,3072,2048)
  const float* W_hh = (const float*)d_in[3];  // (3,2,3072,1024)
  const float* b_ih = (const float*)d_in[4];  // (3,2,3072)
  const float* b_hh = (const float*)d_in[5];  // (3,2,3072)
  float* out = (float*)d_out;                 // (256,32,2048) f32

  // workspace carve
  char* w = (char*)d_ws;
  float* xp = (float*)w;                    w += (size_t)MDIM * NDIM * 4;     // 201.3 MB
  unsigned short* act = (unsigned short*)w; w += (size_t)MDIM * KDIM * 2;     // 33.6 MB
  unsigned short* Wub = (unsigned short*)w; w += (size_t)2 * 3072 * KDIM * 2; // 25.2 MB
  unsigned short* hbA = (unsigned short*)w; w += (size_t)2 * BATCH * HID * 2;
  unsigned short* hbB = (unsigned short*)w; w += (size_t)2 * BATCH * HID * 2;
  unsigned* bar = (unsigned*)w;             w += 3 * 2 * 256;                  // (layer,dir) counters

  // zero the barrier counters (stream-ordered; graph-capture safe)
  hipMemsetAsync(bar, 0, 3 * 2 * 256, stream);

  // x -> bf16 (layer-0 GEMM A operand)
  f32_to_bf16_k<<<16384, 256, 0, stream>>>(x, act, MDIM * KDIM / 4);

  for (int l = 0; l < 3; l++) {
    // W_ih[l] -> bf16 into union buffer
    f32_to_bf16_k<<<12288, 256, 0, stream>>>(
        W_ih + (size_t)l * 2 * 3072 * KDIM, Wub, 2 * 3072 * KDIM / 4);
    // xp = act * W_ih^T + b_ih
    dim3 gg(MDIM / 128, NDIM / 128);
    gemm_xp<<<gg, 256, 0, stream>>>(act, Wub, b_ih + l * NDIM, xp);
    // W_hh[l] -> bf16 into the same union buffer
    f32_to_bf16_k<<<6144, 256, 0, stream>>>(
        W_hh + (size_t)l * 2 * 3072 * HID, Wub, 2 * 3072 * HID / 4);

    // persistent cooperative scan over all 256 steps
    const float* xp_c = xp;
    const unsigned short* Wbf_c = Wub;
    const float* bhl = b_hh + l * NDIM;
    const float* h0l = h0 + (size_t)l * 2 * BATCH * HID;
    unsigned short* hbA_ = hbA; unsigned short* hbB_ = hbB;
    unsigned* bar_ = bar + l * 128;   // 2 dir counters, 256B apart
    unsigned short* dst_bf = (l == 2) ? nullptr : act;
    float* dst_f32 = (l == 2) ? out : nullptr;
    void* args[] = {
        (void*)&xp_c, (void*)&Wbf_c, (void*)&bhl, (void*)&h0l,
        (void*)&hbA_, (void*)&hbB_, (void*)&bar_,
        (void*)&dst_bf, (void*)&dst_f32,
    };
    hipLaunchCooperativeKernel((void*)gru_scan, dim3(128), dim3(384),
                               args, 0, stream);
  }
}